// Round 2
// baseline (2170.122 us; speedup 1.0000x reference)
//
#include <hip/hip_runtime.h>
#include <math.h>

#define BB 4
#define TT 1024
#define DD 1024
#define HH 16
#define LL 6
#define DHH 64
#define MM (BB*TT)   // 4096
#define QKVLD 3072

typedef short bf16x8 __attribute__((ext_vector_type(8)));
typedef float floatx4 __attribute__((ext_vector_type(4)));

__device__ __forceinline__ unsigned short f2bf(float f) {
    unsigned u = __builtin_bit_cast(unsigned, f);
    u += 0x7fffu + ((u >> 16) & 1u);
    return (unsigned short)(u >> 16);
}

// async global->LDS, 16B per lane, wave-uniform LDS base + lane*16
__device__ __forceinline__ void glds16(const unsigned short* g, unsigned short* l) {
    __builtin_amdgcn_global_load_lds(
        (const __attribute__((address_space(1))) void*)g,
        (__attribute__((address_space(3))) void*)l, 16, 0, 0);
}

// ---------------------------------------------------------------- add pos (fp32 out)
__global__ __launch_bounds__(256) void add_pos_kernel(
    const float* __restrict__ seq, const float* __restrict__ pos, float* __restrict__ x)
{
    int i = blockIdx.x * 256 + threadIdx.x;
    const int TD4 = TT * DD / 4;
    float4 s = ((const float4*)seq)[i];
    float4 p = ((const float4*)pos)[i & (TD4 - 1)];
    ((float4*)x)[i] = make_float4(s.x + p.x, s.y + p.y, s.z + p.z, s.w + p.w);
}

// ---------------------------------------------------------------- bias concat (all layers)
__global__ __launch_bounds__(256) void concat_bias_kernel(
    const float* __restrict__ bq, const float* __restrict__ bk,
    const float* __restrict__ bv, float* __restrict__ bqkv)
{
    int i = blockIdx.x * 256 + threadIdx.x;     // LL*3072 total
    int l = i / QKVLD, j = i - l * QKVLD;
    float v;
    if (j < DD)            v = bq[l*DD + j];
    else if (j < 2*DD)     v = bk[l*DD + j - DD];
    else                   v = bv[l*DD + j - 2*DD];
    bqkv[i] = v;
}

// ---------------------------------------------------------------- layernorm (fp32 in, bf16 out)
__global__ __launch_bounds__(256) void ln_kernel(
    const float* __restrict__ x, const float* __restrict__ g,
    const float* __restrict__ b, unsigned short* __restrict__ out)
{
    __shared__ float red[8];
    int row = blockIdx.x;
    int tid = threadIdx.x;
    const float4* xr = (const float4*)(x + (size_t)row * DD);
    float4 v = xr[tid];
    float s  = v.x + v.y + v.z + v.w;
    float ss = v.x*v.x + v.y*v.y + v.z*v.z + v.w*v.w;
    #pragma unroll
    for (int o = 32; o > 0; o >>= 1) {
        s  += __shfl_down(s,  o, 64);
        ss += __shfl_down(ss, o, 64);
    }
    int wid = tid >> 6, lid = tid & 63;
    if (lid == 0) { red[wid] = s; red[4 + wid] = ss; }
    __syncthreads();
    float sum  = red[0] + red[1] + red[2] + red[3];
    float sums = red[4] + red[5] + red[6] + red[7];
    float mean = sum * (1.0f / DD);
    float var  = sums * (1.0f / DD) - mean * mean;
    float inv  = rsqrtf(var + 1e-5f);
    float4 gg = ((const float4*)g)[tid];
    float4 bb = ((const float4*)b)[tid];
    ushort4 o4;
    o4.x = f2bf((v.x - mean) * inv * gg.x + bb.x);
    o4.y = f2bf((v.y - mean) * inv * gg.y + bb.y);
    o4.z = f2bf((v.z - mean) * inv * gg.z + bb.z);
    o4.w = f2bf((v.w - mean) * inv * gg.w + bb.w);
    ((ushort4*)(out + (size_t)row * DD))[tid] = o4;
}

// ---------------------------------------------------------------- per-layer transpose
// All 6 weight matrices of one layer -> wt (bf16, [N][K] each), single dispatch.
// wt layout: [0,3DD2) qkv rows; [3DD2,4DD2) wo; [4DD2,8DD2) w1t; [8DD2,12DD2) w2t
__global__ __launch_bounds__(256) void transpose_layer(
    const float* __restrict__ wq, const float* __restrict__ wk,
    const float* __restrict__ wv, const float* __restrict__ wo,
    const float* __restrict__ w1, const float* __restrict__ w2,
    unsigned short* __restrict__ wt)
{
    __shared__ float tile[32][33];
    const size_t DD2 = (size_t)DD * DD;
    int bid = blockIdx.x;
    const float* src; unsigned short* dst; int K, N, n0, k0;
    if (bid < 4096) {
        int r = bid >> 10, t = bid & 1023;
        src = (r == 0) ? wq : (r == 1) ? wk : (r == 2) ? wv : wo;
        dst = wt + (size_t)r * DD2; K = DD; N = DD;
        n0 = (t & 31) * 32; k0 = (t >> 5) * 32;
    } else if (bid < 8192) {
        int t = bid - 4096;
        src = w1; dst = wt + 4 * DD2; K = DD; N = 4 * DD;
        n0 = (t & 127) * 32; k0 = (t >> 7) * 32;
    } else {
        int t = bid - 8192;
        src = w2; dst = wt + 8 * DD2; K = 4 * DD; N = DD;
        n0 = (t & 31) * 32; k0 = (t >> 5) * 32;
    }
    int tx = threadIdx.x & 31, ty = threadIdx.x >> 5;
    #pragma unroll
    for (int i = 0; i < 4; i++)
        tile[ty + i*8][tx] = src[(size_t)(k0 + ty + i*8) * N + n0 + tx];
    __syncthreads();
    #pragma unroll
    for (int i = 0; i < 4; i++)
        dst[(size_t)(n0 + ty + i*8) * K + k0 + tx] = f2bf(tile[tx][ty + i*8]);
}

// head: single 1024x1024 transpose
__global__ __launch_bounds__(256) void transpose_bf16(
    const float* __restrict__ W, unsigned short* __restrict__ Wt, int K, int N)
{
    __shared__ float tile[32][33];
    int n0 = blockIdx.x * 32, k0 = blockIdx.y * 32;
    int tx = threadIdx.x & 31, ty = threadIdx.x >> 5;
    #pragma unroll
    for (int i = 0; i < 4; i++)
        tile[ty + i*8][tx] = W[(size_t)(k0 + ty + i*8) * N + n0 + tx];
    __syncthreads();
    #pragma unroll
    for (int i = 0; i < 4; i++)
        Wt[(size_t)(n0 + ty + i*8) * K + k0 + tx] = f2bf(tile[tx][ty + i*8]);
}

// ---------------------------------------------------------------- MFMA GEMM
// C[M,N] = act(A[M,K] @ Bt[N,K]^T + bias) (+ res). 128x128 tile, BK=32.
// Depth-3 global_load_lds pipeline: 3 LDS buffer sets, 2 stages always in
// flight, raw s_barrier + counted vmcnt (never 0 in steady state, T4).
// Stage(t+2) issued at step t, awaited at top of step t+2 (~2 K-steps of
// latency cover). One barrier per K-step. XCD-aware 1D grid swizzle.
template<int ACT, int RES, int OUTBF>
__global__ __launch_bounds__(256) void mfma_gemm(
    const unsigned short* __restrict__ A, const unsigned short* __restrict__ Bt,
    const float* __restrict__ bias, const float* __restrict__ res,
    void* __restrict__ Cv, int M, int N, int K)
{
    __shared__ unsigned short As[3][128*32];
    __shared__ unsigned short Bs[3][128*32];
    const int tid = threadIdx.x;
    const int wave = tid >> 6, lane = tid & 63;
    const int quad = lane >> 4, lc = lane & 15;

    // XCD swizzle: xcd gets m-band [xcd*4, xcd*4+4), m-fastest within XCD
    const int bid = blockIdx.x;
    const int xcd = bid & 7;
    const int j = bid >> 3;
    const int m0 = (xcd * 4 + (j & 3)) << 7;
    const int n0 = (j >> 2) << 7;

    // staging: wave w covers rows [w*32, w*32+32); two 16-row calls per matrix.
    // lane i of a call: row = 16*call + w*32 + (i>>2), col-chunk = (i&3)*8.
    const int grow = wave * 32 + (lane >> 2);
    const int gcol = (lane & 3) * 8;
    const unsigned short* Ag = A  + (size_t)(m0 + grow) * K + gcol;
    const unsigned short* Bg = Bt + (size_t)(n0 + grow) * K + gcol;
    const int lbase = wave * 1024;   // elems: wave's 32 rows x 32 cols

    const int wm = (wave & 1) * 64, wn = (wave >> 1) * 64;

    floatx4 acc[4][4];
    #pragma unroll
    for (int i = 0; i < 4; i++)
        #pragma unroll
        for (int jj = 0; jj < 4; jj++) acc[i][jj] = (floatx4)0.0f;

    // 4 glds per stage, FIFO order (vmcnt counts these)
    #define STAGE(buf, koff) do { \
        glds16(Ag + (koff),                 &As[buf][lbase]); \
        glds16(Ag + (koff) + (size_t)16*K,  &As[buf][lbase + 512]); \
        glds16(Bg + (koff),                 &Bs[buf][lbase]); \
        glds16(Bg + (koff) + (size_t)16*K,  &Bs[buf][lbase + 512]); \
    } while (0)

    const int NT = K >> 5;
    // prologue: 2 stages in flight
    STAGE(0, 0);
    STAGE(1, 32);

    int cur = 0;
    for (int t = 0, k0 = 0; t < NT; ++t, k0 += 32) {
        // wait for stage(t) only; stage(t+1) stays in flight
        if (t + 1 < NT) asm volatile("s_waitcnt vmcnt(4)" ::: "memory");
        else            asm volatile("s_waitcnt vmcnt(0)" ::: "memory");
        __builtin_amdgcn_s_barrier();
        __builtin_amdgcn_sched_barrier(0);
        if (t + 2 < NT) {
            int nb = cur + 2; if (nb >= 3) nb -= 3;
            STAGE(nb, k0 + 64);
        }
        bf16x8 af[4], bfr[4];
        #pragma unroll
        for (int i = 0; i < 4; i++)
            af[i] = *(const bf16x8*)&As[cur][(wm + i*16 + lc)*32 + quad*8];
        #pragma unroll
        for (int jj = 0; jj < 4; jj++)
            bfr[jj] = *(const bf16x8*)&Bs[cur][(wn + jj*16 + lc)*32 + quad*8];
        #pragma unroll
        for (int i = 0; i < 4; i++)
            #pragma unroll
            for (int jj = 0; jj < 4; jj++)
                acc[i][jj] = __builtin_amdgcn_mfma_f32_16x16x32_bf16(af[i], bfr[jj], acc[i][jj], 0, 0, 0);
        cur = (cur == 2) ? 0 : cur + 1;
    }
    #undef STAGE

    #pragma unroll
    for (int jj = 0; jj < 4; jj++) {
        int n = n0 + wn + jj*16 + lc;
        float bv = bias ? bias[n] : 0.0f;
        #pragma unroll
        for (int i = 0; i < 4; i++) {
            int mbase = m0 + wm + i*16 + quad*4;
            #pragma unroll
            for (int r = 0; r < 4; r++) {
                int m = mbase + r;
                float v = acc[i][jj][r] + bv;
                if (ACT) v = 0.5f * v * (1.0f + erff(v * 0.70710678118654752f));
                if (RES) v += res[(size_t)m * N + n];
                if (OUTBF) ((unsigned short*)Cv)[(size_t)m * N + n] = f2bf(v);
                else       ((float*)Cv)[(size_t)m * N + n] = v;
            }
        }
    }
}

// ---------------------------------------------------------------- flash attention (bf16 MFMA)
// grid (T/64, B*H). block 256 = 4 waves. qkv packed [B*T][3072]: q|k|v.
#define LSTR 88
__global__ __launch_bounds__(256) void attn_mfma(
    const unsigned short* __restrict__ qkv, unsigned short* __restrict__ y)
{
    __shared__ unsigned short Qs[64*LSTR];
    __shared__ unsigned short Ks[64*LSTR];   // reused as V^T [dh][s]
    __shared__ unsigned short Ps[64*LSTR];
    const int tid = threadIdx.x, wave = tid >> 6, lane = tid & 63;
    const int quad = lane >> 4, lc = lane & 15;
    const int t0 = blockIdx.x * 64;
    const int b = blockIdx.y >> 4, h = blockIdx.y & 15;

    const unsigned short* q = qkv;
    const unsigned short* k = qkv + DD;
    const unsigned short* v = qkv + 2*DD;

    const size_t rowbase = (size_t)b * TT;
    const int sr = tid >> 2, sc = (tid & 3) * 16;

    {   // stage Q [64 t][64 dh]
        const unsigned short* src = q + (rowbase + t0 + sr) * QKVLD + h*DHH + sc;
        *(uint4*)&Qs[sr*LSTR + sc]     = *(const uint4*)src;
        *(uint4*)&Qs[sr*LSTR + sc + 8] = *(const uint4*)(src + 8);
    }

    float m_r[4], l_r[4];
    floatx4 o_acc[4];
    #pragma unroll
    for (int r = 0; r < 4; r++) { m_r[r] = -1e30f; l_r[r] = 0.0f; }
    #pragma unroll
    for (int f = 0; f < 4; f++) o_acc[f] = (floatx4)0.0f;

    for (int s0 = 0; s0 < TT; s0 += 64) {
        __syncthreads();
        {   // stage K [64 s][64 dh]
            const unsigned short* src = k + (rowbase + s0 + sr) * QKVLD + h*DHH + sc;
            *(uint4*)&Ks[sr*LSTR + sc]     = *(const uint4*)src;
            *(uint4*)&Ks[sr*LSTR + sc + 8] = *(const uint4*)(src + 8);
        }
        __syncthreads();

        floatx4 s[4];
        #pragma unroll
        for (int f = 0; f < 4; f++) s[f] = (floatx4)0.0f;
        #pragma unroll
        for (int c = 0; c < 2; c++) {
            bf16x8 aq = *(const bf16x8*)&Qs[(wave*16 + lc)*LSTR + c*32 + quad*8];
            #pragma unroll
            for (int f = 0; f < 4; f++) {
                bf16x8 bk = *(const bf16x8*)&Ks[(f*16 + lc)*LSTR + c*32 + quad*8];
                s[f] = __builtin_amdgcn_mfma_f32_16x16x32_bf16(aq, bk, s[f], 0, 0, 0);
            }
        }

        #pragma unroll
        for (int r = 0; r < 4; r++) {
            float mt = fmaxf(fmaxf(s[0][r], s[1][r]), fmaxf(s[2][r], s[3][r])) * 0.125f;
            #pragma unroll
            for (int d = 1; d < 16; d <<= 1) mt = fmaxf(mt, __shfl_xor(mt, d, 64));
            float mn = fmaxf(m_r[r], mt);
            float alpha = __expf(m_r[r] - mn);
            m_r[r] = mn;
            float rs = 0.0f;
            #pragma unroll
            for (int f = 0; f < 4; f++) {
                float p = __expf(s[f][r] * 0.125f - mn);
                s[f][r] = p;
                rs += p;
            }
            #pragma unroll
            for (int d = 1; d < 16; d <<= 1) rs += __shfl_xor(rs, d, 64);
            l_r[r] = l_r[r] * alpha + rs;
            #pragma unroll
            for (int f = 0; f < 4; f++) o_acc[f][r] *= alpha;
        }

        #pragma unroll
        for (int f = 0; f < 4; f++)
            #pragma unroll
            for (int r = 0; r < 4; r++)
                Ps[(wave*16 + quad*4 + r)*LSTR + f*16 + lc] = f2bf(s[f][r]);

        __syncthreads();
        {   // stage V^T [64 dh][64 s] into Ks
            const unsigned short* src = v + (rowbase + s0 + sr) * QKVLD + h*DHH + sc;
            uint4 v0 = *(const uint4*)src;
            uint4 v1 = *(const uint4*)(src + 8);
            unsigned short tmp[16];
            *(uint4*)&tmp[0] = v0;
            *(uint4*)&tmp[8] = v1;
            #pragma unroll
            for (int e = 0; e < 16; e++)
                Ks[(sc + e)*LSTR + sr] = tmp[e];
        }
        __syncthreads();

        #pragma unroll
        for (int c = 0; c < 2; c++) {
            bf16x8 ap = *(const bf16x8*)&Ps[(wave*16 + lc)*LSTR + c*32 + quad*8];
            #pragma unroll
            for (int f = 0; f < 4; f++) {
                bf16x8 bv = *(const bf16x8*)&Ks[(f*16 + lc)*LSTR + c*32 + quad*8];
                o_acc[f] = __builtin_amdgcn_mfma_f32_16x16x32_bf16(ap, bv, o_acc[f], 0, 0, 0);
            }
        }
    }

    unsigned short* yg = y + (rowbase + t0) * DD + h*DHH;
    #pragma unroll
    for (int f = 0; f < 4; f++)
        #pragma unroll
        for (int r = 0; r < 4; r++)
            yg[(size_t)(wave*16 + quad*4 + r) * DD + f*16 + lc] = f2bf(o_acc[f][r] / l_r[r]);
}

// ---------------------------------------------------------------- launch
extern "C" void kernel_launch(void* const* d_in, const int* in_sizes, int n_in,
                              void* d_out, int out_size, void* d_ws, size_t ws_size,
                              hipStream_t stream)
{
    const float* seq    = (const float*)d_in[0];
    const float* pos    = (const float*)d_in[1];
    const float* ln1_g  = (const float*)d_in[2];
    const float* ln1_b  = (const float*)d_in[3];
    const float* wq     = (const float*)d_in[4];
    const float* bq     = (const float*)d_in[5];
    const float* wk     = (const float*)d_in[6];
    const float* bk     = (const float*)d_in[7];
    const float* wv     = (const float*)d_in[8];
    const float* bv     = (const float*)d_in[9];
    const float* wo     = (const float*)d_in[10];
    const float* bo     = (const float*)d_in[11];
    const float* ln2_g  = (const float*)d_in[12];
    const float* ln2_b  = (const float*)d_in[13];
    const float* w1     = (const float*)d_in[14];
    const float* b1     = (const float*)d_in[15];
    const float* w2     = (const float*)d_in[16];
    const float* b2     = (const float*)d_in[17];
    const float* lnf_g  = (const float*)d_in[18];
    const float* lnf_b  = (const float*)d_in[19];
    const float* w_head = (const float*)d_in[20];
    float* out = (float*)d_out;

    const size_t MSZ = (size_t)MM * DD;
    float* x            = (float*)d_ws;                 // 16 MB fp32
    unsigned short* h   = (unsigned short*)(x + MSZ);   // 8 MB bf16
    unsigned short* qkv = h + MSZ;                      // [4096][3072] bf16, 24 MB
    unsigned short* ub  = qkv + (size_t)MM * QKVLD;     // [4096][4096] bf16, 32 MB
    unsigned short* wt  = ub + (size_t)MM * 4 * DD;     // 12M el, 24 MB
    unsigned short* wto = wt + (size_t)3*DD*DD;
    unsigned short* wt1 = wt + (size_t)4*DD*DD;         // [4096][1024]
    unsigned short* wt2 = wt + (size_t)8*DD*DD;         // [1024][4096]
    float* bqkv         = (float*)(wt + (size_t)12*DD*DD);  // [L][3072] fp32

    dim3 blk(256);
    dim3 g1(32*8);      // N=1024: 256 blocks (1D swizzled)
    dim3 gq(32*24);     // N=3072: 768 blocks
    dim3 g4(32*32);     // N=4096: 1024 blocks
    dim3 tsq(32, 32);
    dim3 ag(16, 64);

    add_pos_kernel<<<4096, blk, 0, stream>>>(seq, pos, x);
    concat_bias_kernel<<<LL*QKVLD/256, blk, 0, stream>>>(bq, bk, bv, bqkv);

    for (int l = 0; l < LL; l++) {
        const size_t wofs  = (size_t)l * DD * DD;
        const size_t bofs  = (size_t)l * DD;
        const size_t w1ofs = (size_t)l * DD * 4 * DD;
        const size_t b1ofs = (size_t)l * 4 * DD;

        transpose_layer<<<12288, blk, 0, stream>>>(
            wq + wofs, wk + wofs, wv + wofs, wo + wofs, w1 + w1ofs, w2 + w1ofs, wt);

        ln_kernel<<<MM, blk, 0, stream>>>(x, ln1_g + bofs, ln1_b + bofs, h);
        mfma_gemm<0,0,1><<<gq, blk, 0, stream>>>(h, wt, bqkv + (size_t)l*QKVLD, nullptr, qkv, MM, QKVLD, DD);
        attn_mfma<<<ag, blk, 0, stream>>>(qkv, h);
        mfma_gemm<0,1,0><<<g1, blk, 0, stream>>>(h, wto, bo + bofs, x, x, MM, DD, DD);
        ln_kernel<<<MM, blk, 0, stream>>>(x, ln2_g + bofs, ln2_b + bofs, h);
        mfma_gemm<1,0,1><<<g4, blk, 0, stream>>>(h, wt1, b1 + b1ofs, nullptr, ub, MM, 4*DD, DD);
        mfma_gemm<0,1,0><<<g1, blk, 0, stream>>>(ub, wt2, b2 + bofs, x, x, MM, DD, 4*DD);
    }

    ln_kernel<<<MM, blk, 0, stream>>>(x, lnf_g, lnf_b, h);
    transpose_bf16<<<tsq, blk, 0, stream>>>(w_head, wt, DD, DD);
    mfma_gemm<0,0,0><<<g1, blk, 0, stream>>>(h, wt, nullptr, nullptr, out, MM, DD, DD);
}

// Round 3
// 1976.022 us; speedup vs baseline: 1.0982x; 1.0982x over previous
//
#include <hip/hip_runtime.h>
#include <math.h>

#define BB 4
#define TT 1024
#define DD 1024
#define HH 16
#define LL 6
#define DHH 64
#define MM (BB*TT)   // 4096
#define QKVLD 3072

typedef short bf16x8 __attribute__((ext_vector_type(8)));
typedef float floatx4 __attribute__((ext_vector_type(4)));

__device__ __forceinline__ unsigned short f2bf(float f) {
    unsigned u = __builtin_bit_cast(unsigned, f);
    u += 0x7fffu + ((u >> 16) & 1u);
    return (unsigned short)(u >> 16);
}

// ---------------------------------------------------------------- add pos (fp32 out)
__global__ __launch_bounds__(256) void add_pos_kernel(
    const float* __restrict__ seq, const float* __restrict__ pos, float* __restrict__ x)
{
    int i = blockIdx.x * 256 + threadIdx.x;
    const int TD4 = TT * DD / 4;
    float4 s = ((const float4*)seq)[i];
    float4 p = ((const float4*)pos)[i & (TD4 - 1)];
    ((float4*)x)[i] = make_float4(s.x + p.x, s.y + p.y, s.z + p.z, s.w + p.w);
}

// ---------------------------------------------------------------- bias concat (all layers)
__global__ __launch_bounds__(256) void concat_bias_kernel(
    const float* __restrict__ bq, const float* __restrict__ bk,
    const float* __restrict__ bv, float* __restrict__ bqkv)
{
    int i = blockIdx.x * 256 + threadIdx.x;     // LL*3072 total
    int l = i / QKVLD, j = i - l * QKVLD;
    float v;
    if (j < DD)            v = bq[l*DD + j];
    else if (j < 2*DD)     v = bk[l*DD + j - DD];
    else                   v = bv[l*DD + j - 2*DD];
    bqkv[i] = v;
}

// ---------------------------------------------------------------- layernorm (fp32 in, bf16 out)
__global__ __launch_bounds__(256) void ln_kernel(
    const float* __restrict__ x, const float* __restrict__ g,
    const float* __restrict__ b, unsigned short* __restrict__ out)
{
    __shared__ float red[8];
    int row = blockIdx.x;
    int tid = threadIdx.x;
    const float4* xr = (const float4*)(x + (size_t)row * DD);
    float4 v = xr[tid];
    float s  = v.x + v.y + v.z + v.w;
    float ss = v.x*v.x + v.y*v.y + v.z*v.z + v.w*v.w;
    #pragma unroll
    for (int o = 32; o > 0; o >>= 1) {
        s  += __shfl_down(s,  o, 64);
        ss += __shfl_down(ss, o, 64);
    }
    int wid = tid >> 6, lid = tid & 63;
    if (lid == 0) { red[wid] = s; red[4 + wid] = ss; }
    __syncthreads();
    float sum  = red[0] + red[1] + red[2] + red[3];
    float sums = red[4] + red[5] + red[6] + red[7];
    float mean = sum * (1.0f / DD);
    float var  = sums * (1.0f / DD) - mean * mean;
    float inv  = rsqrtf(var + 1e-5f);
    float4 gg = ((const float4*)g)[tid];
    float4 bb = ((const float4*)b)[tid];
    ushort4 o4;
    o4.x = f2bf((v.x - mean) * inv * gg.x + bb.x);
    o4.y = f2bf((v.y - mean) * inv * gg.y + bb.y);
    o4.z = f2bf((v.z - mean) * inv * gg.z + bb.z);
    o4.w = f2bf((v.w - mean) * inv * gg.w + bb.w);
    ((ushort4*)(out + (size_t)row * DD))[tid] = o4;
}

// ---------------------------------------------------------------- per-layer transpose
// All 6 weight matrices of one layer -> wt (bf16, [N][K] each), single dispatch.
// wt layout: [0,3DD2) qkv rows; [3DD2,4DD2) wo; [4DD2,8DD2) w1t; [8DD2,12DD2) w2t
__global__ __launch_bounds__(256) void transpose_layer(
    const float* __restrict__ wq, const float* __restrict__ wk,
    const float* __restrict__ wv, const float* __restrict__ wo,
    const float* __restrict__ w1, const float* __restrict__ w2,
    unsigned short* __restrict__ wt)
{
    __shared__ float tile[32][33];
    const size_t DD2 = (size_t)DD * DD;
    int bid = blockIdx.x;
    const float* src; unsigned short* dst; int K, N, n0, k0;
    if (bid < 4096) {
        int r = bid >> 10, t = bid & 1023;
        src = (r == 0) ? wq : (r == 1) ? wk : (r == 2) ? wv : wo;
        dst = wt + (size_t)r * DD2; K = DD; N = DD;
        n0 = (t & 31) * 32; k0 = (t >> 5) * 32;
    } else if (bid < 8192) {
        int t = bid - 4096;
        src = w1; dst = wt + 4 * DD2; K = DD; N = 4 * DD;
        n0 = (t & 127) * 32; k0 = (t >> 7) * 32;
    } else {
        int t = bid - 8192;
        src = w2; dst = wt + 8 * DD2; K = 4 * DD; N = DD;
        n0 = (t & 31) * 32; k0 = (t >> 5) * 32;
    }
    int tx = threadIdx.x & 31, ty = threadIdx.x >> 5;
    #pragma unroll
    for (int i = 0; i < 4; i++)
        tile[ty + i*8][tx] = src[(size_t)(k0 + ty + i*8) * N + n0 + tx];
    __syncthreads();
    #pragma unroll
    for (int i = 0; i < 4; i++)
        dst[(size_t)(n0 + ty + i*8) * K + k0 + tx] = f2bf(tile[tx][ty + i*8]);
}

// head: single 1024x1024 transpose
__global__ __launch_bounds__(256) void transpose_bf16(
    const float* __restrict__ W, unsigned short* __restrict__ Wt, int K, int N)
{
    __shared__ float tile[32][33];
    int n0 = blockIdx.x * 32, k0 = blockIdx.y * 32;
    int tx = threadIdx.x & 31, ty = threadIdx.x >> 5;
    #pragma unroll
    for (int i = 0; i < 4; i++)
        tile[ty + i*8][tx] = W[(size_t)(k0 + ty + i*8) * N + n0 + tx];
    __syncthreads();
    #pragma unroll
    for (int i = 0; i < 4; i++)
        Wt[(size_t)(n0 + ty + i*8) * K + k0 + tx] = f2bf(tile[tx][ty + i*8]);
}

// ---------------------------------------------------------------- MFMA GEMM
// C[M,N] = act(A[M,K] @ Bt[N,K]^T + bias) (+ res). 128xBN tile, BK=32,
// register-staged double-buffered LDS pipeline (1 barrier / K-step, loads
// stay in flight across the barrier), XCD-aware 1D grid swizzle.
// BN=128: grid 32*(N/128) blocks. BN=64 (for N=1024): grid 512 = 2 blocks/CU
// so a co-resident block's MFMA covers this block's staging latency.
template<int BN, int ACT, int RES, int OUTBF>
__global__ __launch_bounds__(256) void mfma_gemm(
    const unsigned short* __restrict__ A, const unsigned short* __restrict__ Bt,
    const float* __restrict__ bias, const float* __restrict__ res,
    void* __restrict__ Cv, int M, int N, int K)
{
    constexpr int NJ = BN / 32;      // n-frags per wave
    __shared__ unsigned short As[2][128*32];
    __shared__ unsigned short Bs[2][BN*32];
    const int tid = threadIdx.x;
    const int wave = tid >> 6, lane = tid & 63;
    const int quad = lane >> 4, lc = lane & 15;

    // XCD swizzle: xcd owns m-band [xcd*4, xcd*4+4), m-fastest within XCD
    const int bid = blockIdx.x;
    const int xcd = bid & 7;
    const int j = bid >> 3;
    const int m0 = (xcd * 4 + (j & 3)) << 7;
    const int n0 = (j >> 2) * BN;

    // staging: thread t loads row (t>>2) [and 64+(t>>2) if 128 rows], chunk (t&3)*8
    const int srow = tid >> 2, scol = (tid & 3) * 8;
    const unsigned short* Ag = A  + (size_t)(m0 + srow) * K + scol;
    const unsigned short* Bg = Bt + (size_t)(n0 + srow) * K + scol;
    const int lds_lo = srow * 32 + scol, lds_hi = (64 + srow) * 32 + scol;

    const int wm = (wave & 1) * 64, wn = (wave >> 1) * (BN >> 1);

    floatx4 acc[4][NJ];
    #pragma unroll
    for (int i = 0; i < 4; i++)
        #pragma unroll
        for (int jj = 0; jj < NJ; jj++) acc[i][jj] = (floatx4)0.0f;

    // prologue: prefetch tile 0 into registers
    uint4 pa0 = *(const uint4*)(Ag);
    uint4 pa1 = *(const uint4*)(Ag + (size_t)64 * K);
    uint4 pb0 = *(const uint4*)(Bg);
    uint4 pb1;
    if (BN == 128) pb1 = *(const uint4*)(Bg + (size_t)64 * K);

    int cur = 0;
    for (int k0 = 0; k0 < K; k0 += 32) {
        *(uint4*)&As[cur][lds_lo] = pa0;
        *(uint4*)&As[cur][lds_hi] = pa1;
        *(uint4*)&Bs[cur][lds_lo] = pb0;
        if (BN == 128) *(uint4*)&Bs[cur][lds_hi] = pb1;
        __syncthreads();
        if (k0 + 32 < K) {
            pa0 = *(const uint4*)(Ag + k0 + 32);
            pa1 = *(const uint4*)(Ag + k0 + 32 + (size_t)64 * K);
            pb0 = *(const uint4*)(Bg + k0 + 32);
            if (BN == 128) pb1 = *(const uint4*)(Bg + k0 + 32 + (size_t)64 * K);
        }
        bf16x8 af[4], bfr[NJ];
        #pragma unroll
        for (int i = 0; i < 4; i++)
            af[i] = *(const bf16x8*)&As[cur][(wm + i*16 + lc)*32 + quad*8];
        #pragma unroll
        for (int jj = 0; jj < NJ; jj++)
            bfr[jj] = *(const bf16x8*)&Bs[cur][(wn + jj*16 + lc)*32 + quad*8];
        #pragma unroll
        for (int i = 0; i < 4; i++)
            #pragma unroll
            for (int jj = 0; jj < NJ; jj++)
                acc[i][jj] = __builtin_amdgcn_mfma_f32_16x16x32_bf16(af[i], bfr[jj], acc[i][jj], 0, 0, 0);
        cur ^= 1;
    }

    #pragma unroll
    for (int jj = 0; jj < NJ; jj++) {
        int n = n0 + wn + jj*16 + lc;
        float bv = bias ? bias[n] : 0.0f;
        #pragma unroll
        for (int i = 0; i < 4; i++) {
            int mbase = m0 + wm + i*16 + quad*4;
            #pragma unroll
            for (int r = 0; r < 4; r++) {
                int m = mbase + r;
                float v = acc[i][jj][r] + bv;
                if (ACT) v = 0.5f * v * (1.0f + erff(v * 0.70710678118654752f));
                if (RES) v += res[(size_t)m * N + n];
                if (OUTBF) ((unsigned short*)Cv)[(size_t)m * N + n] = f2bf(v);
                else       ((float*)Cv)[(size_t)m * N + n] = v;
            }
        }
    }
}

// ---------------------------------------------------------------- flash attention (bf16 MFMA)
// grid (T/64, B*H). block 256 = 4 waves. qkv packed [B*T][3072]: q|k|v.
#define LSTR 88
__global__ __launch_bounds__(256) void attn_mfma(
    const unsigned short* __restrict__ qkv, unsigned short* __restrict__ y)
{
    __shared__ unsigned short Qs[64*LSTR];
    __shared__ unsigned short Ks[64*LSTR];   // reused as V^T [dh][s]
    __shared__ unsigned short Ps[64*LSTR];
    const int tid = threadIdx.x, wave = tid >> 6, lane = tid & 63;
    const int quad = lane >> 4, lc = lane & 15;
    const int t0 = blockIdx.x * 64;
    const int b = blockIdx.y >> 4, h = blockIdx.y & 15;

    const unsigned short* q = qkv;
    const unsigned short* k = qkv + DD;
    const unsigned short* v = qkv + 2*DD;

    const size_t rowbase = (size_t)b * TT;
    const int sr = tid >> 2, sc = (tid & 3) * 16;

    {   // stage Q [64 t][64 dh]
        const unsigned short* src = q + (rowbase + t0 + sr) * QKVLD + h*DHH + sc;
        *(uint4*)&Qs[sr*LSTR + sc]     = *(const uint4*)src;
        *(uint4*)&Qs[sr*LSTR + sc + 8] = *(const uint4*)(src + 8);
    }

    float m_r[4], l_r[4];
    floatx4 o_acc[4];
    #pragma unroll
    for (int r = 0; r < 4; r++) { m_r[r] = -1e30f; l_r[r] = 0.0f; }
    #pragma unroll
    for (int f = 0; f < 4; f++) o_acc[f] = (floatx4)0.0f;

    for (int s0 = 0; s0 < TT; s0 += 64) {
        __syncthreads();
        {   // stage K [64 s][64 dh]
            const unsigned short* src = k + (rowbase + s0 + sr) * QKVLD + h*DHH + sc;
            *(uint4*)&Ks[sr*LSTR + sc]     = *(const uint4*)src;
            *(uint4*)&Ks[sr*LSTR + sc + 8] = *(const uint4*)(src + 8);
        }
        __syncthreads();

        floatx4 s[4];
        #pragma unroll
        for (int f = 0; f < 4; f++) s[f] = (floatx4)0.0f;
        #pragma unroll
        for (int c = 0; c < 2; c++) {
            bf16x8 aq = *(const bf16x8*)&Qs[(wave*16 + lc)*LSTR + c*32 + quad*8];
            #pragma unroll
            for (int f = 0; f < 4; f++) {
                bf16x8 bk = *(const bf16x8*)&Ks[(f*16 + lc)*LSTR + c*32 + quad*8];
                s[f] = __builtin_amdgcn_mfma_f32_16x16x32_bf16(aq, bk, s[f], 0, 0, 0);
            }
        }

        #pragma unroll
        for (int r = 0; r < 4; r++) {
            float mt = fmaxf(fmaxf(s[0][r], s[1][r]), fmaxf(s[2][r], s[3][r])) * 0.125f;
            #pragma unroll
            for (int d = 1; d < 16; d <<= 1) mt = fmaxf(mt, __shfl_xor(mt, d, 64));
            float mn = fmaxf(m_r[r], mt);
            float alpha = __expf(m_r[r] - mn);
            m_r[r] = mn;
            float rs = 0.0f;
            #pragma unroll
            for (int f = 0; f < 4; f++) {
                float p = __expf(s[f][r] * 0.125f - mn);
                s[f][r] = p;
                rs += p;
            }
            #pragma unroll
            for (int d = 1; d < 16; d <<= 1) rs += __shfl_xor(rs, d, 64);
            l_r[r] = l_r[r] * alpha + rs;
            #pragma unroll
            for (int f = 0; f < 4; f++) o_acc[f][r] *= alpha;
        }

        #pragma unroll
        for (int f = 0; f < 4; f++)
            #pragma unroll
            for (int r = 0; r < 4; r++)
                Ps[(wave*16 + quad*4 + r)*LSTR + f*16 + lc] = f2bf(s[f][r]);

        __syncthreads();
        {   // stage V^T [64 dh][64 s] into Ks
            const unsigned short* src = v + (rowbase + s0 + sr) * QKVLD + h*DHH + sc;
            uint4 v0 = *(const uint4*)src;
            uint4 v1 = *(const uint4*)(src + 8);
            unsigned short tmp[16];
            *(uint4*)&tmp[0] = v0;
            *(uint4*)&tmp[8] = v1;
            #pragma unroll
            for (int e = 0; e < 16; e++)
                Ks[(sc + e)*LSTR + sr] = tmp[e];
        }
        __syncthreads();

        #pragma unroll
        for (int c = 0; c < 2; c++) {
            bf16x8 ap = *(const bf16x8*)&Ps[(wave*16 + lc)*LSTR + c*32 + quad*8];
            #pragma unroll
            for (int f = 0; f < 4; f++) {
                bf16x8 bv = *(const bf16x8*)&Ks[(f*16 + lc)*LSTR + c*32 + quad*8];
                o_acc[f] = __builtin_amdgcn_mfma_f32_16x16x32_bf16(ap, bv, o_acc[f], 0, 0, 0);
            }
        }
    }

    unsigned short* yg = y + (rowbase + t0) * DD + h*DHH;
    #pragma unroll
    for (int f = 0; f < 4; f++)
        #pragma unroll
        for (int r = 0; r < 4; r++)
            yg[(size_t)(wave*16 + quad*4 + r) * DD + f*16 + lc] = f2bf(o_acc[f][r] / l_r[r]);
}

// ---------------------------------------------------------------- launch
extern "C" void kernel_launch(void* const* d_in, const int* in_sizes, int n_in,
                              void* d_out, int out_size, void* d_ws, size_t ws_size,
                              hipStream_t stream)
{
    const float* seq    = (const float*)d_in[0];
    const float* pos    = (const float*)d_in[1];
    const float* ln1_g  = (const float*)d_in[2];
    const float* ln1_b  = (const float*)d_in[3];
    const float* wq     = (const float*)d_in[4];
    const float* bq     = (const float*)d_in[5];
    const float* wk     = (const float*)d_in[6];
    const float* bk     = (const float*)d_in[7];
    const float* wv     = (const float*)d_in[8];
    const float* bv     = (const float*)d_in[9];
    const float* wo     = (const float*)d_in[10];
    const float* bo     = (const float*)d_in[11];
    const float* ln2_g  = (const float*)d_in[12];
    const float* ln2_b  = (const float*)d_in[13];
    const float* w1     = (const float*)d_in[14];
    const float* b1     = (const float*)d_in[15];
    const float* w2     = (const float*)d_in[16];
    const float* b2     = (const float*)d_in[17];
    const float* lnf_g  = (const float*)d_in[18];
    const float* lnf_b  = (const float*)d_in[19];
    const float* w_head = (const float*)d_in[20];
    float* out = (float*)d_out;

    const size_t MSZ = (size_t)MM * DD;
    float* x            = (float*)d_ws;                 // 16 MB fp32
    unsigned short* h   = (unsigned short*)(x + MSZ);   // 8 MB bf16
    unsigned short* qkv = h + MSZ;                      // [4096][3072] bf16, 24 MB
    unsigned short* ub  = qkv + (size_t)MM * QKVLD;     // [4096][4096] bf16, 32 MB
    unsigned short* wt  = ub + (size_t)MM * 4 * DD;     // 12M el, 24 MB
    unsigned short* wto = wt + (size_t)3*DD*DD;
    unsigned short* wt1 = wt + (size_t)4*DD*DD;         // [4096][1024]
    unsigned short* wt2 = wt + (size_t)8*DD*DD;         // [1024][4096]
    float* bqkv         = (float*)(wt + (size_t)12*DD*DD);  // [L][3072] fp32

    dim3 blk(256);
    dim3 g64(32*16);    // N=1024, BN=64: 512 blocks (2 blocks/CU)
    dim3 gq(32*24);     // N=3072, BN=128: 768 blocks
    dim3 g4(32*32);     // N=4096, BN=128: 1024 blocks
    dim3 tsq(32, 32);
    dim3 ag(16, 64);

    add_pos_kernel<<<4096, blk, 0, stream>>>(seq, pos, x);
    concat_bias_kernel<<<LL*QKVLD/256, blk, 0, stream>>>(bq, bk, bv, bqkv);

    for (int l = 0; l < LL; l++) {
        const size_t wofs  = (size_t)l * DD * DD;
        const size_t bofs  = (size_t)l * DD;
        const size_t w1ofs = (size_t)l * DD * 4 * DD;
        const size_t b1ofs = (size_t)l * 4 * DD;

        transpose_layer<<<12288, blk, 0, stream>>>(
            wq + wofs, wk + wofs, wv + wofs, wo + wofs, w1 + w1ofs, w2 + w1ofs, wt);

        ln_kernel<<<MM, blk, 0, stream>>>(x, ln1_g + bofs, ln1_b + bofs, h);
        mfma_gemm<128,0,0,1><<<gq, blk, 0, stream>>>(h, wt, bqkv + (size_t)l*QKVLD, nullptr, qkv, MM, QKVLD, DD);
        attn_mfma<<<ag, blk, 0, stream>>>(qkv, h);
        mfma_gemm<64,0,1,0><<<g64, blk, 0, stream>>>(h, wto, bo + bofs, x, x, MM, DD, DD);
        ln_kernel<<<MM, blk, 0, stream>>>(x, ln2_g + bofs, ln2_b + bofs, h);
        mfma_gemm<128,1,0,1><<<g4, blk, 0, stream>>>(h, wt1, b1 + b1ofs, nullptr, ub, MM, 4*DD, DD);
        mfma_gemm<64,0,1,0><<<g64, blk, 0, stream>>>(ub, wt2, b2 + bofs, x, x, MM, DD, 4*DD);
    }

    ln_kernel<<<MM, blk, 0, stream>>>(x, lnf_g, lnf_b, h);
    transpose_bf16<<<tsq, blk, 0, stream>>>(w_head, wt, DD, DD);
    mfma_gemm<64,0,0,0><<<g64, blk, 0, stream>>>(h, wt, nullptr, nullptr, out, MM, DD, DD);
}